// Round 6
// baseline (70.121 us; speedup 1.0000x reference)
//
#include <hip/hip_runtime.h>
#include <cmath>

#define B_    4
#define CIN   8
#define COUT  16
#define H_    192
#define W_    192
#define TILE  32
#define PAD   2
#define SX    36
#define SY    36
#define NCO   2
#define NT    128
#define NF2   648            // SY*SX/2 float2 elements per tile

__global__ __launch_bounds__(NT)
void semiconv_kernel(const float* __restrict__ x,
                     const float* __restrict__ scales,
                     float* __restrict__ out) {
    __shared__ float tile[2][SY * SX];   // 2 * 5184 B = 10.1 KB
    __shared__ float wtab[NCO * CIN];    // 64 B

    int blk = blockIdx.x;
    const int tile_x = blk % 6; blk /= 6;
    const int tile_y = blk % 6; blk /= 6;
    const int cg     = blk & 7; blk >>= 3;   // 8 co-groups of 2
    const int b      = blk;

    const int tid = threadIdx.x;

    if (tid < NCO * CIN)
        wtab[tid] = 0.25f / scales[(cg * NCO + (tid >> 3)) * CIN + (tid & 7)];

    const int gy0  = tile_y * TILE - PAD;    // global row of lds row 0
    const int gxp0 = 16 * tile_x - 1;        // global float2-col of lds col 0

    // staging coords: float2 element e = tid + 128k, k=0..5 (k=5: tid<8 only)
    int  gidx[6]; bool okk[6];
    {
        int ey = tid / 18, ex = tid - (tid / 18) * 18;
        #pragma unroll
        for (int k = 0; k < 6; ++k) {
            int gy = gy0 + ey, gxp = gxp0 + ex;
            okk[k]  = (gy >= 0) && (gy < H_) && (gxp >= 0) && (gxp < W_ / 2);
            gidx[k] = gy * (W_ / 2) + gxp;
            ey += 7; ex += 2;                  // advance by 128 = 7*18 + 2
            if (ex >= 18) { ex -= 18; ++ey; }
        }
    }
    const bool tail = tid < (NF2 - 5 * NT);    // 8 threads handle the tail

    const float2* xb = (const float2*)(x + (size_t)b * CIN * H_ * W_);
    const int chan_f2 = H_ * W_ / 2;
    const float2 NEG2 = make_float2(-INFINITY, -INFINITY);

    // ---- prologue: stage ci=0 into buffer 0 ----
    {
        float2 st[6];
        #pragma unroll
        for (int k = 0; k < 5; ++k) st[k] = okk[k] ? xb[gidx[k]] : NEG2;
        st[5] = (tail && okk[5]) ? xb[gidx[5]] : NEG2;
        float2* dst = (float2*)tile[0];
        #pragma unroll
        for (int k = 0; k < 5; ++k) dst[tid + k * NT] = st[k];
        if (tail) dst[tid + 5 * NT] = st[5];
    }
    __syncthreads();

    float w0[CIN], w1[CIN];
    #pragma unroll
    for (int i = 0; i < CIN; ++i) { w0[i] = wtab[i]; w1[i] = wtab[CIN + i]; }

    // per-thread read base: rows 2*(tid>>3).., cols 4*(tid&7).. (pre-shifted)
    const float* tb = tile[0] + ((tid >> 3) * 2) * SX + (tid & 7) * 4;

    float s[NCO][2][4];
    #pragma unroll
    for (int c = 0; c < NCO; ++c)
        #pragma unroll
        for (int r = 0; r < 2; ++r)
            #pragma unroll
            for (int j = 0; j < 4; ++j) s[c][r][j] = 0.f;

    #pragma unroll
    for (int ci = 0; ci < CIN; ++ci) {
        // T14: issue next-ci global loads before compute (latency hides)
        float2 pf[6];
        if (ci + 1 < CIN) {
            const float2* xp = xb + (size_t)(ci + 1) * chan_f2;
            #pragma unroll
            for (int k = 0; k < 5; ++k) pf[k] = okk[k] ? xp[gidx[k]] : NEG2;
            pf[5] = (tail && okk[5]) ? xp[gidx[5]] : NEG2;
        }

        const float* tp = tb + (ci & 1) * (SY * SX);
        const float a10 = w0[ci], a40 = 4.f * w0[ci];
        const float a11 = w1[ci], a41 = 4.f * w1[ci];

        float t0[6][4], t1[6][4];
        #pragma unroll
        for (int r = 0; r < 6; ++r) {
            const float4 lo = *(const float4*)(tp + r * SX);
            const float4 hi = *(const float4*)(tp + r * SX + 4);
            const float c0 = lo.x, c1 = lo.y, c2 = lo.z, c3 = lo.w;
            const float c4 = hi.x, c5 = hi.y, c6 = hi.z, c7 = hi.w;
            // shared horizontal partials (center c[j+2], +-1, +-2)
            const float p1a = fmaxf(c1, c3), p2a = fmaxf(c0, c4);
            const float p1b = fmaxf(c2, c4), p2b = fmaxf(c1, c5);
            const float p1c = fmaxf(c3, c5), p2c = fmaxf(c2, c6);
            const float p1d = fmaxf(c4, c6), p2d = fmaxf(c3, c7);
            t0[r][0] = fmaxf(fmaxf(p1a - a10, p2a - a40), c2);
            t0[r][1] = fmaxf(fmaxf(p1b - a10, p2b - a40), c3);
            t0[r][2] = fmaxf(fmaxf(p1c - a10, p2c - a40), c4);
            t0[r][3] = fmaxf(fmaxf(p1d - a10, p2d - a40), c5);
            t1[r][0] = fmaxf(fmaxf(p1a - a11, p2a - a41), c2);
            t1[r][1] = fmaxf(fmaxf(p1b - a11, p2b - a41), c3);
            t1[r][2] = fmaxf(fmaxf(p1c - a11, p2c - a41), c4);
            t1[r][3] = fmaxf(fmaxf(p1d - a11, p2d - a41), c5);
        }
        #pragma unroll
        for (int j = 0; j < 4; ++j) {
            float v1, v4;
            v1 = fmaxf(t0[1][j], t0[3][j]); v4 = fmaxf(t0[0][j], t0[4][j]);
            s[0][0][j] += fmaxf(fmaxf(v1 - a10, v4 - a40), t0[2][j]);
            v1 = fmaxf(t0[2][j], t0[4][j]); v4 = fmaxf(t0[1][j], t0[5][j]);
            s[0][1][j] += fmaxf(fmaxf(v1 - a10, v4 - a40), t0[3][j]);
            v1 = fmaxf(t1[1][j], t1[3][j]); v4 = fmaxf(t1[0][j], t1[4][j]);
            s[1][0][j] += fmaxf(fmaxf(v1 - a11, v4 - a41), t1[2][j]);
            v1 = fmaxf(t1[2][j], t1[4][j]); v4 = fmaxf(t1[1][j], t1[5][j]);
            s[1][1][j] += fmaxf(fmaxf(v1 - a11, v4 - a41), t1[3][j]);
        }

        if (ci + 1 < CIN) {
            float2* dst = (float2*)tile[(ci + 1) & 1];
            #pragma unroll
            for (int k = 0; k < 5; ++k) dst[tid + k * NT] = pf[k];
            if (tail) dst[tid + 5 * NT] = pf[5];
            __syncthreads();
        }
    }

    const int orow = tile_y * TILE + (tid >> 3) * 2;
    const int ocol = tile_x * TILE + (tid & 7) * 4;
    #pragma unroll
    for (int c = 0; c < NCO; ++c) {
        float* op = out + ((size_t)((b * COUT + cg * NCO + c) * H_) + orow) * W_ + ocol;
        *(float4*)(op)      = make_float4(s[c][0][0], s[c][0][1], s[c][0][2], s[c][0][3]);
        *(float4*)(op + W_) = make_float4(s[c][1][0], s[c][1][1], s[c][1][2], s[c][1][3]);
    }
}

extern "C" void kernel_launch(void* const* d_in, const int* in_sizes, int n_in,
                              void* d_out, int out_size, void* d_ws, size_t ws_size,
                              hipStream_t stream) {
    const float* x      = (const float*)d_in[0];
    const float* scales = (const float*)d_in[1];
    float* out          = (float*)d_out;

    const int n_blocks = B_ * (COUT / NCO) * (H_ / TILE) * (W_ / TILE);  // 4*8*6*6 = 1152
    semiconv_kernel<<<n_blocks, NT, 0, stream>>>(x, scales, out);
}

// Round 7
// 17.696 us; speedup vs baseline: 3.9625x; 3.9625x over previous
//
#include <hip/hip_runtime.h>
#include <cmath>

#define B_    4
#define CIN   8
#define COUT  16
#define H_    192
#define W_    192
#define TW    32
#define TH    16
#define SX    36                 // tile row: 32 + 4 halo floats
#define SY    20                 // tile col: 16 + 4 halo rows
#define NCO   4
#define NT    128
#define SLAB  (SY * SX)          // 720 floats per ci
#define NF2   (SLAB / 2)         // 360 float2
#define CHAN_F2 (H_ * W_ / 2)    // 18432

__global__ __launch_bounds__(NT, 2)
void semiconv_kernel(const float* __restrict__ x,
                     const float* __restrict__ scales,
                     float* __restrict__ out) {
    __shared__ float tile[CIN * SLAB];     // 23040 B
    __shared__ float wtab[NCO * CIN];      // 128 B

    int blk = blockIdx.x;
    const int tile_x = blk % 6;  blk /= 6;
    const int tile_y = blk % 12; blk /= 12;
    const int cg     = blk & 3;  blk >>= 2;
    const int b      = blk;

    const int tid = threadIdx.x;
    const int py  = tid >> 3;            // 0..15 output row in tile
    const int p0  = (tid & 7) * 4;       // output col group (0,4,..,28)

    // weight table: a = 0.25/s, computed once by 32 threads
    if (tid < NCO * CIN)
        wtab[tid] = 0.25f / scales[cg * NCO * CIN + tid];

    // ---- staging coords (float2 granularity) ----
    const int gy0  = tile_y * TH - 2;
    const int gxp0 = tile_x * (TW / 2) - 1;
    int gidx[3]; bool okk[3];
    {
        int e = tid;
        #pragma unroll
        for (int k = 0; k < 3; ++k) {
            int ey = e / 18, ex = e - ey * 18;
            int gy = gy0 + ey, gxp = gxp0 + ex;
            okk[k]  = (gy >= 0) && (gy < H_) && (gxp >= 0) && (gxp < W_ / 2);
            gidx[k] = gy * (W_ / 2) + gxp;
            e += NT;
        }
    }
    const bool tail = tid < (NF2 - 2 * NT);   // 104 threads

    // ---- load ALL 8 ci slabs to regs (loads all in flight), then write LDS ----
    const float2* xb = (const float2*)(x + (size_t)b * CIN * H_ * W_);
    const float2 NEG2 = make_float2(-INFINITY, -INFINITY);
    float2 pf[CIN][3];
    #pragma unroll
    for (int ci = 0; ci < CIN; ++ci) {
        const float2* xp = xb + ci * CHAN_F2;
        pf[ci][0] = okk[0] ? xp[gidx[0]] : NEG2;
        pf[ci][1] = okk[1] ? xp[gidx[1]] : NEG2;
        pf[ci][2] = (tail && okk[2]) ? xp[gidx[2]] : NEG2;
    }
    float2* lp = (float2*)tile;
    #pragma unroll
    for (int ci = 0; ci < CIN; ++ci) {
        lp[ci * NF2 + tid]          = pf[ci][0];
        lp[ci * NF2 + tid + NT]     = pf[ci][1];
        if (tail) lp[ci * NF2 + tid + 2 * NT] = pf[ci][2];
    }

    __syncthreads();   // the only barrier

    // weights to registers
    float wa[NCO][CIN];
    #pragma unroll
    for (int c = 0; c < NCO; ++c)
        #pragma unroll
        for (int ci = 0; ci < CIN; ++ci)
            wa[c][ci] = wtab[c * CIN + ci];

    float acc[NCO][4];
    #pragma unroll
    for (int c = 0; c < NCO; ++c)
        #pragma unroll
        for (int p = 0; p < 4; ++p) acc[c][p] = 0.f;

    const float* tb = tile + py * SX + p0;

    #pragma unroll
    for (int ci = 0; ci < CIN; ++ci) {
        const float* tp = tb + ci * SLAB;

        // 5 rows x 8 cols window, b128 loads, all-static indexing
        float X[5][8];
        #pragma unroll
        for (int r = 0; r < 5; ++r) {
            float4 lo = *(const float4*)(tp + r * SX);
            float4 hi = *(const float4*)(tp + r * SX + 4);
            X[r][0] = lo.x; X[r][1] = lo.y; X[r][2] = lo.z; X[r][3] = lo.w;
            X[r][4] = hi.x; X[r][5] = hi.y; X[r][6] = hi.z; X[r][7] = hi.w;
        }

        // vertical class partials per column (co-independent)
        float V0[8], V1[8], V4[8];
        #pragma unroll
        for (int c = 0; c < 8; ++c) {
            V0[c] = X[2][c];
            V1[c] = fmaxf(X[1][c], X[3][c]);
            V4[c] = fmaxf(X[0][c], X[4][c]);
        }

        // per-co weight multiples (adds, shared over the 4 px)
        float A1[NCO], A2[NCO], A4[NCO], A5[NCO], A8[NCO];
        #pragma unroll
        for (int c = 0; c < NCO; ++c) {
            float a = wa[c][ci];
            A1[c] = a;
            A2[c] = a + a;
            A4[c] = A2[c] + A2[c];
            A5[c] = A4[c] + a;
            A8[c] = A4[c] + A4[c];
        }

        #pragma unroll
        for (int p = 0; p < 4; ++p) {
            const int c = p + 2;
            // weight-class maxes (co-independent)
            float M0 = V0[c];
            float M1 = fmaxf(fmaxf(V0[c - 1], V0[c + 1]), V1[c]);         // max3
            float M2 = fmaxf(V1[c - 1], V1[c + 1]);
            float M4 = fmaxf(fmaxf(V0[c - 2], V0[c + 2]), V4[c]);         // max3
            float M5 = fmaxf(fmaxf(V1[c - 2], V1[c + 2]),
                             fmaxf(V4[c - 1], V4[c + 1]));
            float M8 = fmaxf(V4[c - 2], V4[c + 2]);
            #pragma unroll
            for (int co = 0; co < NCO; ++co) {
                float lo3 = fmaxf(fmaxf(M1 - A1[co], M2 - A2[co]), M0);   // max3
                float hi3 = fmaxf(fmaxf(M4 - A4[co], M5 - A5[co]),
                                  M8 - A8[co]);                            // max3
                acc[co][p] += fmaxf(lo3, hi3);
            }
        }
    }

    const int gy = tile_y * TH + py;
    const int gx = tile_x * TW + p0;
    #pragma unroll
    for (int co = 0; co < NCO; ++co) {
        float* op = out + ((size_t)((b * COUT + cg * NCO + co) * H_) + gy) * W_ + gx;
        *(float4*)op = make_float4(acc[co][0], acc[co][1], acc[co][2], acc[co][3]);
    }
}

extern "C" void kernel_launch(void* const* d_in, const int* in_sizes, int n_in,
                              void* d_out, int out_size, void* d_ws, size_t ws_size,
                              hipStream_t stream) {
    const float* x      = (const float*)d_in[0];
    const float* scales = (const float*)d_in[1];
    float* out          = (float*)d_out;

    const int n_blocks = B_ * (COUT / NCO) * (H_ / TH) * (W_ / TW);  // 4*4*12*6 = 1152
    semiconv_kernel<<<n_blocks, NT, 0, stream>>>(x, scales, out);
}

// Round 8
// 16.954 us; speedup vs baseline: 4.1359x; 1.0437x over previous
//
#include <hip/hip_runtime.h>
#include <cmath>

#define B_    4
#define CIN   8
#define COUT  16
#define H_    192
#define W_    192
#define TW    32
#define TH    16
#define SX    36                 // 32 + 4 halo cols
#define SY    20                 // 16 + 4 halo rows
#define NCO   4
#define NT    256
#define SLAB  (SY * SX)          // 720 floats per ci
#define NF2   (SLAB / 2)         // 360 float2
#define CHAN_F2 (H_ * W_ / 2)    // 18432

__global__ __launch_bounds__(NT, 4)
void semiconv_kernel(const float* __restrict__ x,
                     const float* __restrict__ scales,
                     float* __restrict__ out) {
    __shared__ float tile[CIN * SLAB];     // 23040 B
    __shared__ float wtab[NCO * CIN];      // 128 B

    int blk = blockIdx.x;
    const int tile_x = blk % 6;  blk /= 6;
    const int tile_y = blk % 12; blk /= 12;
    const int cg     = blk & 3;  blk >>= 2;
    const int b      = blk;

    const int tid = threadIdx.x;
    const int lt  = tid & 127;           // thread within half-block
    const int grp = tid >> 7;            // 0: ci 0-3, 1: ci 4-7
    const int py  = lt >> 3;             // 0..15 output row in tile
    const int p0  = (lt & 7) * 4;        // output col group

    if (tid < NCO * CIN)
        wtab[tid] = 0.25f / scales[cg * NCO * CIN + tid];

    // ---- staging coords (float2 granularity): elements tid, tid+256 of 360 ----
    const int gy0  = tile_y * TH - 2;
    const int gxp0 = tile_x * (TW / 2) - 1;
    int gidx[2]; bool okk[2];
    {
        int e = tid;
        #pragma unroll
        for (int k = 0; k < 2; ++k) {
            int ey = e / 18, ex = e - ey * 18;
            int gy = gy0 + ey, gxp = gxp0 + ex;
            okk[k]  = (gy >= 0) && (gy < H_) && (gxp >= 0) && (gxp < W_ / 2);
            gidx[k] = gy * (W_ / 2) + gxp;
            e += NT;
        }
    }
    const bool tail = tid < (NF2 - NT);   // 104 threads

    // ---- load ALL 8 ci slabs to regs, then write LDS, one barrier ----
    const float2* xb = (const float2*)(x + (size_t)b * CIN * H_ * W_);
    const float2 NEG2 = make_float2(-INFINITY, -INFINITY);
    float2 pf[CIN][2];
    #pragma unroll
    for (int ci = 0; ci < CIN; ++ci) {
        const float2* xp = xb + ci * CHAN_F2;
        pf[ci][0] = okk[0] ? xp[gidx[0]] : NEG2;
        pf[ci][1] = (tail && okk[1]) ? xp[gidx[1]] : NEG2;
    }
    float2* lp = (float2*)tile;
    #pragma unroll
    for (int ci = 0; ci < CIN; ++ci) {
        lp[ci * NF2 + tid] = pf[ci][0];
        if (tail) lp[ci * NF2 + tid + NT] = pf[ci][1];
    }

    __syncthreads();

    // this group's 4 ci weights
    float wa[NCO][4];
    #pragma unroll
    for (int c = 0; c < NCO; ++c)
        #pragma unroll
        for (int k = 0; k < 4; ++k)
            wa[c][k] = wtab[c * CIN + grp * 4 + k];

    float acc[NCO][4];
    #pragma unroll
    for (int c = 0; c < NCO; ++c)
        #pragma unroll
        for (int p = 0; p < 4; ++p) acc[c][p] = 0.f;

    const float* tb = tile + grp * 4 * SLAB + py * SX + p0;

    #pragma unroll
    for (int k = 0; k < 4; ++k) {
        const float* tp = tb + k * SLAB;

        float X[5][8];
        #pragma unroll
        for (int r = 0; r < 5; ++r) {
            float4 lo = *(const float4*)(tp + r * SX);
            float4 hi = *(const float4*)(tp + r * SX + 4);
            X[r][0] = lo.x; X[r][1] = lo.y; X[r][2] = lo.z; X[r][3] = lo.w;
            X[r][4] = hi.x; X[r][5] = hi.y; X[r][6] = hi.z; X[r][7] = hi.w;
        }

        // vertical class partials per column (co-independent)
        float V0[8], V1[8], V4[8];
        #pragma unroll
        for (int c = 0; c < 8; ++c) {
            V0[c] = X[2][c];
            V1[c] = fmaxf(X[1][c], X[3][c]);
            V4[c] = fmaxf(X[0][c], X[4][c]);
        }

        float A1[NCO], A2[NCO], A4[NCO], A5[NCO], A8[NCO];
        #pragma unroll
        for (int c = 0; c < NCO; ++c) {
            float a = wa[c][k];
            A1[c] = a;
            A2[c] = a + a;
            A4[c] = A2[c] + A2[c];
            A5[c] = A4[c] + a;
            A8[c] = A4[c] + A4[c];
        }

        #pragma unroll
        for (int p = 0; p < 4; ++p) {
            const int c = p + 2;
            float M0 = V0[c];
            float M1 = fmaxf(fmaxf(V0[c - 1], V0[c + 1]), V1[c]);
            float M2 = fmaxf(V1[c - 1], V1[c + 1]);
            float M4 = fmaxf(fmaxf(V0[c - 2], V0[c + 2]), V4[c]);
            float M5 = fmaxf(fmaxf(V1[c - 2], V1[c + 2]),
                             fmaxf(V4[c - 1], V4[c + 1]));
            float M8 = fmaxf(V4[c - 2], V4[c + 2]);
            #pragma unroll
            for (int co = 0; co < NCO; ++co) {
                float lo3 = fmaxf(fmaxf(M1 - A1[co], M2 - A2[co]), M0);
                float hi3 = fmaxf(fmaxf(M4 - A4[co], M5 - A5[co]),
                                  M8 - A8[co]);
                acc[co][p] += fmaxf(lo3, hi3);
            }
        }
    }

    // ---- combine: group 1 writes partials into (its own) ci4 slab region ----
    float* cbuf = tile + 4 * SLAB;       // 128*16 floats = 8 KB, inside ci4-5 slabs
    if (grp == 1) {
        float4* cb = (float4*)(cbuf + lt * 16);
        #pragma unroll
        for (int co = 0; co < NCO; ++co)
            cb[co] = make_float4(acc[co][0], acc[co][1], acc[co][2], acc[co][3]);
    }
    __syncthreads();
    if (grp == 0) {
        const float4* cb = (const float4*)(cbuf + lt * 16);
        const int gy = tile_y * TH + py;
        const int gx = tile_x * TW + p0;
        #pragma unroll
        for (int co = 0; co < NCO; ++co) {
            float4 o = cb[co];
            float* op = out + ((size_t)((b * COUT + cg * NCO + co) * H_) + gy) * W_ + gx;
            *(float4*)op = make_float4(acc[co][0] + o.x, acc[co][1] + o.y,
                                       acc[co][2] + o.z, acc[co][3] + o.w);
        }
    }
}

extern "C" void kernel_launch(void* const* d_in, const int* in_sizes, int n_in,
                              void* d_out, int out_size, void* d_ws, size_t ws_size,
                              hipStream_t stream) {
    const float* x      = (const float*)d_in[0];
    const float* scales = (const float*)d_in[1];
    float* out          = (float*)d_out;

    const int n_blocks = B_ * (COUT / NCO) * (H_ / TH) * (W_ / TW);  // 1152
    semiconv_kernel<<<n_blocks, NT, 0, stream>>>(x, scales, out);
}

// Round 9
// 16.021 us; speedup vs baseline: 4.3767x; 1.0582x over previous
//
#include <hip/hip_runtime.h>
#include <cmath>

typedef float v2f __attribute__((ext_vector_type(2)));

#define B_    4
#define CIN   8
#define COUT  16
#define H_    192
#define W_    192
#define TW    32
#define TH    16
#define SX    36
#define SY    20
#define SLAB  (SY * SX)          // 720 floats per ci slab
#define NF2   (SLAB / 2)         // 360
#define NCO   8
#define NT    512
#define CHAN_F2 (H_ * W_ / 2)    // 18432

__global__ __launch_bounds__(NT, 4)
void semiconv_kernel(const float* __restrict__ x,
                     const float* __restrict__ scales,
                     float* __restrict__ out) {
    __shared__ __align__(16) float tile[CIN * SLAB];          // 23040 B
    __shared__ __align__(16) float wtab[CIN][NCO];            // 256 B [ci][co]
    __shared__ __align__(16) float cbuf[3 * NCO * 128 * 4];   // 49152 B

    int blk = blockIdx.x;
    const int tile_x = blk % 6;  blk /= 6;
    const int tile_y = blk % 12; blk /= 12;
    const int cg     = blk & 1;  blk >>= 1;
    const int b      = blk;

    const int tid = threadIdx.x;
    const int lt  = tid & 127;
    const int grp = tid >> 7;          // 0..3; handles ci = 2*grp, 2*grp+1
    const int py  = lt >> 3;           // 0..15 output row
    const int p0  = (lt & 7) * 4;      // output col group

    if (tid < CIN * NCO) {             // wtab[ci][co] = 0.25/s
        int ci = tid >> 3, co = tid & 7;
        wtab[ci][co] = 0.25f / scales[(cg * NCO + co) * CIN + ci];
    }

    // ---- staging: threads 0..359 stage float2-elem `tid` of ALL 8 slabs ----
    if (tid < NF2) {
        const int ey  = tid / 18, ex = tid - (tid / 18) * 18;
        const int gy  = tile_y * TH - 2 + ey;
        const int gxp = tile_x * (TW / 2) - 1 + ex;
        const bool ok = (gy >= 0) && (gy < H_) && (gxp >= 0) && (gxp < W_ / 2);
        const int gofs = gy * (W_ / 2) + gxp;
        const float2* xb = (const float2*)(x + (size_t)b * CIN * H_ * W_);
        const float2 NEG2 = make_float2(-INFINITY, -INFINITY);
        float2 v[CIN];
        #pragma unroll
        for (int ci = 0; ci < CIN; ++ci)
            v[ci] = ok ? xb[ci * CHAN_F2 + gofs] : NEG2;
        float2* lp = (float2*)tile;
        #pragma unroll
        for (int ci = 0; ci < CIN; ++ci)
            lp[ci * NF2 + tid] = v[ci];
    }

    __syncthreads();

    v2f acc[NCO][2];
    #pragma unroll
    for (int co = 0; co < NCO; ++co) {
        acc[co][0] = (v2f){0.f, 0.f};
        acc[co][1] = (v2f){0.f, 0.f};
    }

    const float* tbg = tile + grp * 2 * SLAB + py * SX + p0;

    #pragma unroll
    for (int k = 0; k < 2; ++k) {
        const float* tp = tbg + k * SLAB;

        float X[5][8];
        #pragma unroll
        for (int r = 0; r < 5; ++r) {
            float4 lo = *(const float4*)(tp + r * SX);
            float4 hi = *(const float4*)(tp + r * SX + 4);
            X[r][0] = lo.x; X[r][1] = lo.y; X[r][2] = lo.z; X[r][3] = lo.w;
            X[r][4] = hi.x; X[r][5] = hi.y; X[r][6] = hi.z; X[r][7] = hi.w;
        }

        // vertical class partials (co-independent)
        float V0[8], V1[8], V4[8];
        #pragma unroll
        for (int c = 0; c < 8; ++c) {
            V0[c] = X[2][c];
            V1[c] = fmaxf(X[1][c], X[3][c]);
            V4[c] = fmaxf(X[0][c], X[4][c]);
        }

        // horizontal class maxes, packed per px-pair (pr0: c=2,3; pr1: c=4,5)
        v2f M0[2], M1[2], M2[2], M4[2], M5[2], M8[2];
        #pragma unroll
        for (int pr = 0; pr < 2; ++pr) {
            const int c0 = 2 + 2 * pr;
            M0[pr] = (v2f){V0[c0], V0[c0 + 1]};
            M1[pr] = (v2f){fmaxf(fmaxf(V0[c0 - 1], V0[c0 + 1]), V1[c0]),
                           fmaxf(fmaxf(V0[c0],     V0[c0 + 2]), V1[c0 + 1])};
            M2[pr] = (v2f){fmaxf(V1[c0 - 1], V1[c0 + 1]),
                           fmaxf(V1[c0],     V1[c0 + 2])};
            M4[pr] = (v2f){fmaxf(fmaxf(V0[c0 - 2], V0[c0 + 2]), V4[c0]),
                           fmaxf(fmaxf(V0[c0 - 1], V0[c0 + 3]), V4[c0 + 1])};
            M5[pr] = (v2f){fmaxf(fmaxf(fmaxf(V1[c0 - 2], V1[c0 + 2]), V4[c0 - 1]), V4[c0 + 1]),
                           fmaxf(fmaxf(fmaxf(V1[c0 - 1], V1[c0 + 3]), V4[c0]),     V4[c0 + 2])};
            M8[pr] = (v2f){fmaxf(V4[c0 - 2], V4[c0 + 2]),
                           fmaxf(V4[c0 - 1], V4[c0 + 3])};
        }

        const float* wrow = &wtab[grp * 2 + k][0];
        float4 wv0 = *(const float4*)(wrow);
        float4 wv1 = *(const float4*)(wrow + 4);

        #pragma unroll
        for (int co = 0; co < NCO; ++co) {
            const float a = (co < 4) ? (&wv0.x)[co] : (&wv1.x)[co - 4];
            const v2f aa = (v2f){a, a};
            #pragma unroll
            for (int pr = 0; pr < 2; ++pr) {
                v2f s1 = M1[pr] - aa;              // pk_add(neg)
                v2f s2 = M2[pr] - 2.f * aa;        // pk_fma
                v2f s4 = M4[pr] - 4.f * aa;        // pk_fma
                v2f s5 = M5[pr] - 5.f * aa;        // pk_fma
                v2f s8 = M8[pr] - 8.f * aa;        // pk_fma
                float lox = fmaxf(fmaxf(s1.x, s2.x), M0[pr].x);   // max3
                float hix = fmaxf(fmaxf(s4.x, s5.x), s8.x);       // max3
                float loy = fmaxf(fmaxf(s1.y, s2.y), M0[pr].y);
                float hiy = fmaxf(fmaxf(s4.y, s5.y), s8.y);
                v2f vm;
                vm.x = fmaxf(lox, hix);
                vm.y = fmaxf(loy, hiy);
                acc[co][pr] += vm;                 // pk_add
            }
        }
    }

    // ---- combine the 4 ci-partials ----
    if (grp != 0) {
        float* cb = cbuf + (((grp - 1) * NCO) * 128 + lt) * 4;
        #pragma unroll
        for (int co = 0; co < NCO; ++co) {
            float* p = cb + co * 128 * 4;
            *(v2f*)p       = acc[co][0];
            *(v2f*)(p + 2) = acc[co][1];
        }
    }
    __syncthreads();
    if (grp == 0) {
        const int gy = tile_y * TH + py;
        const int gx = tile_x * TW + p0;
        #pragma unroll
        for (int co = 0; co < NCO; ++co) {
            #pragma unroll
            for (int g = 1; g < 4; ++g) {
                float4 t = *(const float4*)(cbuf + (((g - 1) * NCO + co) * 128 + lt) * 4);
                acc[co][0] += (v2f){t.x, t.y};
                acc[co][1] += (v2f){t.z, t.w};
            }
            float4 o;
            o.x = acc[co][0].x; o.y = acc[co][0].y;
            o.z = acc[co][1].x; o.w = acc[co][1].y;
            float* op = out + ((size_t)((b * COUT + cg * NCO + co) * H_) + gy) * W_ + gx;
            *(float4*)op = o;
        }
    }
}

extern "C" void kernel_launch(void* const* d_in, const int* in_sizes, int n_in,
                              void* d_out, int out_size, void* d_ws, size_t ws_size,
                              hipStream_t stream) {
    const float* x      = (const float*)d_in[0];
    const float* scales = (const float*)d_in[1];
    float* out          = (float*)d_out;

    const int n_blocks = B_ * 2 * (H_ / TH) * (W_ / TW);  // 4*2*12*6 = 576
    semiconv_kernel<<<n_blocks, NT, 0, stream>>>(x, scales, out);
}